// Round 7
// baseline (85.567 us; speedup 1.0000x reference)
//
#include <hip/hip_runtime.h>
#include <math.h>

#define NROWS 4096
#define DIM   512
#define PROWS 64            // rows per block panel (A in LDS)
#define PCOLS 1024          // cols per block
#define NRP   (NROWS / PROWS)   // 64 row panels
#define NCC   (NROWS / PCOLS)   // 4 col chunks
#define MAXP  4096          // LDS pair buffer entries per block

typedef __attribute__((ext_vector_type(4))) float f32x4;
typedef __attribute__((ext_vector_type(8))) short bf16x8;

// ws layout (bytes):
// [0,      16384)    float mag[4096]
// [16384,  32768)    float row_neg[4096]
// [32768,  32776)    double loss
// [32776,  32780)    unsigned int pair_cnt
// [32800,  98336)    float part[4][4096]      (per-colchunk negsum partials)
// [98336,  4292640)  unsigned short Xb[4096*512]  (bf16 copy of X)
// [4292640, ...)     pairs: uint2 {(i<<16)|j, float_bits(dist)}  8 B each
#define PART_OFF 32800
#define XB_OFF   (PART_OFF + NCC * NROWS * 4)     // 98336
#define PAIR_OFF (XB_OFF + NROWS * DIM * 2)       // 4292640

__device__ inline unsigned short f2bf(float f) {
    unsigned int u = __float_as_uint(f);
    unsigned int r = (u + 0x7fffu + ((u >> 16) & 1u)) >> 16;   // RTNE
    return (unsigned short)r;
}

// fused: bf16 convert + row sq-norms (reads X once)
__global__ void prep_kernel(const float* __restrict__ X,
                            unsigned short* __restrict__ Xb,
                            float* __restrict__ mag) {
    int row  = blockIdx.x * 4 + (threadIdx.x >> 6);
    int lane = threadIdx.x & 63;
    const float4* p = reinterpret_cast<const float4*>(X + (size_t)row * DIM);
    short4* o = reinterpret_cast<short4*>(Xb + (size_t)row * DIM);
    float s = 0.f;
#pragma unroll
    for (int q = lane; q < DIM / 4; q += 64) {
        float4 v = p[q];
        s += v.x * v.x + v.y * v.y + v.z * v.z + v.w * v.w;
        short4 b;
        b.x = (short)f2bf(v.x); b.y = (short)f2bf(v.y);
        b.z = (short)f2bf(v.z); b.w = (short)f2bf(v.w);
        o[q] = b;
    }
#pragma unroll
    for (int off = 32; off; off >>= 1) s += __shfl_down(s, off);
    if (lane == 0) mag[row] = s;
}

// Barrier-free panel GEMM: A panel stationary in LDS, B register-direct from
// L2, 8 independent waves x 2 j-tiles of 64x64 each. Fused loss epilogue.
__global__ __launch_bounds__(512) void sim_panel(
        const unsigned short* __restrict__ Xb, const int* __restrict__ tgt,
        const float* __restrict__ mag, float* __restrict__ part,
        unsigned int* __restrict__ pair_cnt, uint2* __restrict__ pairs,
        unsigned int cap) {
    __shared__ unsigned short As[PROWS * DIM];   // 64 KB
    __shared__ uint2 pairbuf[MAXP];              // 32 KB
    __shared__ float rowpart[8][PROWS];          // 2 KB
    __shared__ unsigned int pcnt;
    __shared__ unsigned int gbase_s;

    const int tid  = threadIdx.x;
    const int lane = tid & 63;
    const int w    = tid >> 6;        // 8 waves
    const int l15  = lane & 15;
    const int lg   = lane >> 4;       // 0..3

    const int rp = blockIdx.x >> 2;   // row panel 0..63
    const int cc = blockIdx.x & 3;    // col chunk 0..3
    const int rowBase  = rp * PROWS;
    const int colBlock = cc * PCOLS;

    if (tid == 0) pcnt = 0;

    // ---- stage A panel once: wave w stages row r = rd*8 + w per round ----
    // LDS slot (row r, chunk c) holds global chunk (c&56)|((c^r)&7)  (both-
    // sides XOR swizzle, linear LDS dest - rule #21)
#pragma unroll
    for (int rd = 0; rd < 8; rd++) {
        int r = rd * 8 + w;
        int c = lane;                      // 0..63, 16B chunks of the 1KB row
        int gch = (c & 56) | ((c ^ r) & 7);
        const unsigned short* src = Xb + (size_t)(rowBase + r) * DIM + gch * 8;
        __builtin_amdgcn_global_load_lds(
            (const __attribute__((address_space(1))) void*)src,
            (__attribute__((address_space(3))) void*)(As + r * DIM),
            16, 0, 0);
    }
    __syncthreads();   // drains vmcnt; pcnt=0 visible

    // A LDS address precompute (element offsets), k-step addr =
    // aRow[m] + (k&14)*32 + (k odd ? aOffO[m] : aOffE[m])
    int aRow[4], aOffE[4], aOffO[4];
#pragma unroll
    for (int m = 0; m < 4; m++) {
        int ra = m * 16 + l15;
        aRow[m]  = ra * DIM;
        aOffE[m] = ((lg) ^ (ra & 7)) * 8;
        aOffO[m] = ((4 | lg) ^ (ra & 7)) * 8;
    }

    float negrow[4][4];
#pragma unroll
    for (int m = 0; m < 4; m++)
#pragma unroll
        for (int q = 0; q < 4; q++) negrow[m][q] = 0.f;

    for (int jj = 0; jj < 2; jj++) {
        const int jt = w * 2 + jj;
        const int colBase = colBlock + jt * 64;
        const unsigned short* pB0 = Xb + (size_t)(colBase + l15) * DIM + lg * 8;
        const unsigned short* pBn[4] = {pB0, pB0 + 16 * DIM, pB0 + 32 * DIM,
                                        pB0 + 48 * DIM};

        f32x4 acc[4][4];
#pragma unroll
        for (int m = 0; m < 4; m++)
#pragma unroll
            for (int n = 0; n < 4; n++) acc[m][n] = (f32x4){0.f, 0.f, 0.f, 0.f};

        bf16x8 aq[2][4], bq[4][4];
#define LOADA(s, k)                                                           \
    { _Pragma("unroll") for (int m = 0; m < 4; m++)                           \
        aq[s][m] = *reinterpret_cast<const bf16x8*>(                          \
            &As[aRow[m] + ((k) & 14) * 32 + (((k) & 1) ? aOffO[m] : aOffE[m])]); }
#define LOADB(s, k)                                                           \
    { _Pragma("unroll") for (int n = 0; n < 4; n++)                           \
        bq[s][n] = *reinterpret_cast<const bf16x8*>(pBn[n] + (k) * 32); }

        LOADB(0, 0) LOADB(1, 1) LOADB(2, 2)
        LOADA(0, 0) LOADA(1, 1)
#pragma unroll
        for (int k = 0; k < 16; k++) {
            if (k + 3 < 16) LOADB((k + 3) & 3, k + 3)   // pre-issue, free slot
#pragma unroll
            for (int m = 0; m < 4; m++)
#pragma unroll
                for (int n = 0; n < 4; n++)
                    acc[m][n] = __builtin_amdgcn_mfma_f32_16x16x32_bf16(
                        aq[k & 1][m], bq[k & 3][n], acc[m][n], 0, 0, 0);
            if (k + 2 < 16) LOADA(k & 1, k + 2)         // reload freed slot
        }
#undef LOADA
#undef LOADB

        // ---- per-jtile epilogue ----
        // C/D layout: col = l15 (within n-th 16), row = lg*4 + q (within m-th 16)
        int tgj[4], gcol[4];
        float mj[4];
#pragma unroll
        for (int n = 0; n < 4; n++) {
            gcol[n] = colBase + n * 16 + l15;
            tgj[n]  = tgt[gcol[n]];
            mj[n]   = mag[gcol[n]];
        }
        int tgi[4][4], gi[4][4];
        float mi[4][4];
#pragma unroll
        for (int m = 0; m < 4; m++)
#pragma unroll
            for (int q = 0; q < 4; q++) {
                gi[m][q]  = rowBase + m * 16 + lg * 4 + q;
                tgi[m][q] = tgt[gi[m][q]];
                mi[m][q]  = mag[gi[m][q]];
            }

        int mycnt = 0;
#pragma unroll
        for (int m = 0; m < 4; m++)
#pragma unroll
            for (int n = 0; n < 4; n++)
#pragma unroll
                for (int q = 0; q < 4; q++) {
                    float sim  = acc[m][n][q];
                    float d2   = mi[m][q] + mj[n] - 2.f * sim;
                    float dist = d2 > 0.f ? sqrtf(d2) : 0.f;
                    if (tgi[m][q] != tgj[n]) {
                        if (dist != 0.f) negrow[m][q] += __expf(1.0f - dist);
                    } else if (gi[m][q] < gcol[n]) {
                        mycnt++;
                    }
                }

        // wave prefix-scan, LDS-atomic append of positive pairs
        unsigned int pc = (unsigned int)mycnt;
        unsigned int incl = pc;
#pragma unroll
        for (int d = 1; d < 64; d <<= 1) {
            unsigned int tv = __shfl_up(incl, d);
            if (lane >= d) incl += tv;
        }
        unsigned int wbase = 0;
        if (lane == 63 && incl) wbase = atomicAdd(&pcnt, incl);
        wbase = __shfl(wbase, 63);
        if (pc) {
            unsigned int idx = wbase + incl - pc;
#pragma unroll
            for (int m = 0; m < 4; m++)
#pragma unroll
                for (int n = 0; n < 4; n++)
#pragma unroll
                    for (int q = 0; q < 4; q++) {
                        if (tgi[m][q] == tgj[n] && gi[m][q] < gcol[n]) {
                            if (idx < MAXP) {
                                float sim  = acc[m][n][q];
                                float d2   = mi[m][q] + mj[n] - 2.f * sim;
                                float dist = d2 > 0.f ? sqrtf(d2) : 0.f;
                                uint2 e;
                                e.x = ((unsigned int)gi[m][q] << 16) |
                                      (unsigned int)gcol[n];
                                e.y = (unsigned int)__float_as_int(dist);
                                pairbuf[idx] = e;
                            }
                            idx++;
                        }
                    }
        }
    }

    // ---- block epilogue: negsum partial store (collision-free) ----
#pragma unroll
    for (int m = 0; m < 4; m++)
#pragma unroll
        for (int q = 0; q < 4; q++) {
            float v = negrow[m][q];
            v += __shfl_xor(v, 1); v += __shfl_xor(v, 2);
            v += __shfl_xor(v, 4); v += __shfl_xor(v, 8);
            if (l15 == 0) rowpart[w][m * 16 + lg * 4 + q] = v;
        }
    __syncthreads();
    if (tid < PROWS) {
        float s = 0.f;
#pragma unroll
        for (int w8 = 0; w8 < 8; w8++) s += rowpart[w8][tid];
        part[(size_t)cc * NROWS + rowBase + tid] = s;
    }

    // pair flush: ONE global atomic per block, then coalesced copy
    if (tid == 0) {
        unsigned int c = pcnt; if (c > MAXP) c = MAXP;
        gbase_s = c ? atomicAdd(pair_cnt, c) : 0u;
    }
    __syncthreads();
    unsigned int cnt = pcnt; if (cnt > MAXP) cnt = MAXP;
    for (unsigned int p = tid; p < cnt; p += 512)
        if (gbase_s + p < cap) pairs[gbase_s + p] = pairbuf[p];
}

// row_neg[r] = sum of 4 col-chunk partials
__global__ void reduce_kernel(const float* __restrict__ part,
                              float* __restrict__ row_neg) {
    int r = blockIdx.x * 256 + threadIdx.x;
    row_neg[r] = part[r] + part[NROWS + r] + part[2 * NROWS + r] +
                 part[3 * NROWS + r];
}

__global__ void pair_kernel(const uint2* __restrict__ pairs,
                            const unsigned int* __restrict__ pair_cnt,
                            const float* __restrict__ row_neg,
                            unsigned int cap, double* __restrict__ loss) {
    __shared__ double red[256];
    unsigned int n = *pair_cnt;
    if (n > cap) n = cap;
    double local = 0.0;
    for (unsigned int p = blockIdx.x * blockDim.x + threadIdx.x; p < n;
         p += gridDim.x * blockDim.x) {
        uint2 e = pairs[p];
        int i = (int)(e.x >> 16), j = (int)(e.x & 0xffffu);
        float d = __int_as_float((int)e.y);
        float J = logf(row_neg[i] + row_neg[j]) + d;
        if (J > 0.f) local += (double)J * (double)J;
    }
    red[threadIdx.x] = local;
    __syncthreads();
    for (int s = 128; s; s >>= 1) {
        if (threadIdx.x < (unsigned)s) red[threadIdx.x] += red[threadIdx.x + s];
        __syncthreads();
    }
    if (threadIdx.x == 0) atomicAdd(loss, red[0]);
}

__global__ void fin_kernel(const double* __restrict__ loss,
                           const unsigned int* __restrict__ pair_cnt,
                           float* __restrict__ out) {
    out[0] = (float)(*loss / (2.0 * (double)(*pair_cnt)));
}

extern "C" void kernel_launch(void* const* d_in, const int* in_sizes, int n_in,
                              void* d_out, int out_size, void* d_ws, size_t ws_size,
                              hipStream_t stream) {
    const float* X = (const float*)d_in[0];
    const int* tgt = (const int*)d_in[1];
    float* out = (float*)d_out;

    char* ws = (char*)d_ws;
    float* mag             = (float*)(ws + 0);
    float* row_neg         = (float*)(ws + 16384);
    double* loss           = (double*)(ws + 32768);
    unsigned int* pair_cnt = (unsigned int*)(ws + 32776);
    float* part            = (float*)(ws + PART_OFF);
    unsigned short* Xb     = (unsigned short*)(ws + XB_OFF);
    uint2* pairs           = (uint2*)(ws + PAIR_OFF);
    unsigned int cap = 0;
    if (ws_size > PAIR_OFF + 8) cap = (unsigned int)((ws_size - PAIR_OFF) / 8);

    hipMemsetAsync(ws + 32768, 0, 16, stream);  // loss + pair_cnt

    prep_kernel<<<NROWS / 4, 256, 0, stream>>>(X, Xb, mag);

    sim_panel<<<NRP * NCC, 512, 0, stream>>>(Xb, tgt, mag, part, pair_cnt,
                                             pairs, cap);

    reduce_kernel<<<NROWS / 256, 256, 0, stream>>>(part, row_neg);

    pair_kernel<<<256, 256, 0, stream>>>(pairs, pair_cnt, row_neg, cap, loss);

    fin_kernel<<<1, 1, 0, stream>>>(loss, pair_cnt, out);
}

// Round 8
// 73.589 us; speedup vs baseline: 1.1628x; 1.1628x over previous
//
#include <hip/hip_runtime.h>
#include <math.h>

#define NROWS 4096
#define DIM   512
#define BM    128
#define BK    128
#define NKT   (DIM / BK)        // 4
#define NTILE (NROWS / BM)      // 32
#define NBLK  (NTILE * (NTILE + 1) / 2)  // 528 triangular blocks

typedef __attribute__((ext_vector_type(4))) float f32x4;
typedef __attribute__((ext_vector_type(8))) short bf16x8;

// ws layout (bytes):
// [0,      16384)    float mag[4096]
// [16384,  32768)    float row_neg[4096]
// [32768,  32776)    double loss
// [32776,  32780)    unsigned int pair_cnt
// [32800,  294944)   ushort part[32][4096]   (bf16 per-tile negsum partials)
// [294944, 4489248)  unsigned short Xb[4096*512]  (bf16 copy of X)
// [4489248, ...)     pairs: uint2 {(i<<16)|j, float_bits(dist)}  8 B each
#define PART_OFF 32800
#define XB_OFF   (PART_OFF + NTILE * NROWS * 2)          // 294944
#define PAIR_OFF (XB_OFF + NROWS * DIM * 2)              // 4489248

__device__ inline unsigned short f2bf(float f) {
    unsigned int u = __float_as_uint(f);
    unsigned int r = (u + 0x7fffu + ((u >> 16) & 1u)) >> 16;   // RTNE
    return (unsigned short)r;
}
__device__ inline float bf2f(unsigned short u) {
    return __uint_as_float((unsigned int)u << 16);
}

// fused: bf16 convert + row sq-norms (reads X once)
__global__ void prep_kernel(const float* __restrict__ X,
                            unsigned short* __restrict__ Xb,
                            float* __restrict__ mag) {
    int row  = blockIdx.x * 4 + (threadIdx.x >> 6);
    int lane = threadIdx.x & 63;
    const float4* p = reinterpret_cast<const float4*>(X + (size_t)row * DIM);
    short4* o = reinterpret_cast<short4*>(Xb + (size_t)row * DIM);
    float s = 0.f;
#pragma unroll
    for (int q = lane; q < DIM / 4; q += 64) {
        float4 v = p[q];
        s += v.x * v.x + v.y * v.y + v.z * v.z + v.w * v.w;
        short4 b;
        b.x = (short)f2bf(v.x); b.y = (short)f2bf(v.y);
        b.z = (short)f2bf(v.z); b.w = (short)f2bf(v.w);
        o[q] = b;
    }
#pragma unroll
    for (int off = 32; off; off >>= 1) s += __shfl_down(s, off);
    if (lane == 0) mag[row] = s;
}

__global__ __launch_bounds__(256, 2) void sim_mfma(
        const unsigned short* __restrict__ Xb, const int* __restrict__ tgt,
        const float* __restrict__ mag, unsigned short* __restrict__ part,
        unsigned int* __restrict__ pair_cnt, uint2* __restrict__ pairs,
        unsigned int cap) {
    __shared__ unsigned short As[BM * BK];   // 32 KB
    __shared__ unsigned short Bs[BM * BK];   // 32 KB
    __shared__ float rowbuf[2][BM];          // [wc][row-local]
    __shared__ float colbuf[2][BM];          // [wr][col-local]
    __shared__ unsigned int scan[8];         // wave totals + base

    const int tid  = threadIdx.x;
    const int lane = tid & 63;
    const int wid  = tid >> 6;        // 4 waves: 2x2 of 64x64
    const int wr   = wid >> 1, wc = wid & 1;
    const int l15  = lane & 15;
    const int lg   = lane >> 4;       // 0..3

    // triangular block mapping: t -> (bi, bj), bi <= bj (NTILE=32)
    int t = blockIdx.x;
    int bi = (int)((65.0f - sqrtf(4225.0f - 8.0f * (float)t)) * 0.5f);
    if (bi < 0) bi = 0;
    if (bi > NTILE - 1) bi = NTILE - 1;
    while ((65 * (bi + 1) - (bi + 1) * (bi + 1)) / 2 <= t) bi++;
    while ((65 * bi - bi * bi) / 2 > t) bi--;
    int bj = bi + (t - (65 * bi - bi * bi) / 2);
    const int rowBase = bi * BM;
    const int colBase = bj * BM;
    const bool offd = (bi != bj);

    f32x4 acc[4][4];
#pragma unroll
    for (int m = 0; m < 4; m++)
#pragma unroll
        for (int n = 0; n < 4; n++) acc[m][n] = (f32x4){0.f, 0.f, 0.f, 0.f};

    // 4 K-steps: sync / stage / sync / compute.  Row = 128 elems = 16 x 16B
    // chunks; LDS slot (r, ch) holds global chunk (ch&8)|((ch^r)&7) (rule #21).
    for (int kt = 0; kt < NKT; kt++) {
        const int k0 = kt * BK;
        __syncthreads();   // previous iteration's reads done before overwrite
#pragma unroll
        for (int p = 0; p < 8; p++) {
            int base = p * 256 + wid * 64;       // wave-uniform chunk base
            int idx  = base + lane;              // 0..2047
            int r    = idx >> 4;
            int ch   = idx & 15;
            int gch  = (ch & 8) | ((ch ^ r) & 7);
            const unsigned short* ga = Xb + (size_t)(rowBase + r) * DIM + k0 + gch * 8;
            __builtin_amdgcn_global_load_lds(
                (const __attribute__((address_space(1))) void*)ga,
                (__attribute__((address_space(3))) void*)(As + base * 8),
                16, 0, 0);
            const unsigned short* gb = Xb + (size_t)(colBase + r) * DIM + k0 + gch * 8;
            __builtin_amdgcn_global_load_lds(
                (const __attribute__((address_space(1))) void*)gb,
                (__attribute__((address_space(3))) void*)(Bs + base * 8),
                16, 0, 0);
        }
        __syncthreads();   // compiler drains vmcnt before barrier

#pragma unroll
        for (int ksub = 0; ksub < 4; ksub++) {
            bf16x8 af[4], bf[4];
#pragma unroll
            for (int m = 0; m < 4; m++) {
                int ra = wr * 64 + m * 16 + l15;
                int c  = ksub * 4 + lg;
                int cs = (c & 8) | ((c ^ ra) & 7);
                af[m] = *reinterpret_cast<const bf16x8*>(&As[ra * BK + cs * 8]);
            }
#pragma unroll
            for (int n = 0; n < 4; n++) {
                int rb = wc * 64 + n * 16 + l15;
                int c  = ksub * 4 + lg;
                int cs = (c & 8) | ((c ^ rb) & 7);
                bf[n] = *reinterpret_cast<const bf16x8*>(&Bs[rb * BK + cs * 8]);
            }
#pragma unroll
            for (int m = 0; m < 4; m++)
#pragma unroll
                for (int n = 0; n < 4; n++)
                    acc[m][n] = __builtin_amdgcn_mfma_f32_16x16x32_bf16(
                        af[m], bf[n], acc[m][n], 0, 0, 0);
        }
    }

    // ---- fused epilogue ----
    // C/D layout: col = lane&15, row = (lane>>4)*4 + reg
    int   gcol[4], tgj[4];
    float mj[4];
#pragma unroll
    for (int n = 0; n < 4; n++) {
        gcol[n] = colBase + wc * 64 + n * 16 + l15;
        tgj[n]  = tgt[gcol[n]];
        mj[n]   = mag[gcol[n]];
    }
    int   grow[4][4], tgi[4][4];
    float mi[4][4];
#pragma unroll
    for (int m = 0; m < 4; m++)
#pragma unroll
        for (int q = 0; q < 4; q++) {
            grow[m][q] = rowBase + wr * 64 + m * 16 + lg * 4 + q;
            tgi[m][q]  = tgt[grow[m][q]];
            mi[m][q]   = mag[grow[m][q]];
        }

    float negrow[4][4];
    float negcol[4] = {0.f, 0.f, 0.f, 0.f};
#pragma unroll
    for (int m = 0; m < 4; m++)
#pragma unroll
        for (int q = 0; q < 4; q++) negrow[m][q] = 0.f;

    int mycnt = 0;
#pragma unroll
    for (int m = 0; m < 4; m++)
#pragma unroll
        for (int n = 0; n < 4; n++)
#pragma unroll
            for (int q = 0; q < 4; q++) {
                float sim  = acc[m][n][q];
                float d2   = mi[m][q] + mj[n] - 2.f * sim;
                float dist = d2 > 0.f ? sqrtf(d2) : 0.f;
                if (tgi[m][q] != tgj[n]) {
                    if (dist != 0.f) {
                        float e = __expf(1.0f - dist);
                        negrow[m][q] += e;
                        if (offd) negcol[n] += e;
                    }
                } else if (grow[m][q] < gcol[n]) {
                    mycnt++;
                }
            }

    __syncthreads();   // LDS (As/Bs) reads done; safe to reuse shared space

    // row-side: reduce across the 16 l15 lanes -> rowbuf[wc][row-local]
#pragma unroll
    for (int m = 0; m < 4; m++)
#pragma unroll
        for (int q = 0; q < 4; q++) {
            float v = negrow[m][q];
            v += __shfl_xor(v, 1); v += __shfl_xor(v, 2);
            v += __shfl_xor(v, 4); v += __shfl_xor(v, 8);
            if (l15 == 0) rowbuf[wc][wr * 64 + m * 16 + lg * 4 + q] = v;
        }
    // col-side: reduce across the 4 lg groups -> colbuf[wr][col-local]
#pragma unroll
    for (int n = 0; n < 4; n++) {
        float v = negcol[n];
        v += __shfl_xor(v, 16); v += __shfl_xor(v, 32);
        if (lg == 0) colbuf[wr][wc * 64 + n * 16 + l15] = v;
    }

    // pair-count scan: wave-level inclusive prefix, then block scan
    unsigned int pc = (unsigned int)mycnt;
    unsigned int incl = pc;
#pragma unroll
    for (int d = 1; d < 64; d <<= 1) {
        unsigned int tshf = __shfl_up(incl, d);
        if (lane >= d) incl += tshf;
    }
    if (lane == 63) scan[wid] = incl;
    __syncthreads();

    // collision-free partial stores: slot part[k][r] written by exactly 1 block
    if (tid < BM) {
        float rv = rowbuf[0][tid] + rowbuf[1][tid];
        part[(size_t)bj * NROWS + rowBase + tid] = f2bf(rv);
        if (offd) {
            float cv = colbuf[0][tid] + colbuf[1][tid];
            part[(size_t)bi * NROWS + colBase + tid] = f2bf(cv);
        }
    }

    unsigned int woff = 0;
#pragma unroll
    for (int w = 0; w < 4; w++)
        if (w < wid) woff += scan[w];
    unsigned int btot = scan[0] + scan[1] + scan[2] + scan[3];
    if (tid == 0) scan[4] = btot ? atomicAdd(pair_cnt, btot) : 0u;
    __syncthreads();
    unsigned int mybase = scan[4] + woff + (incl - pc);

    if (pc) {
        unsigned int idx = mybase;
#pragma unroll
        for (int m = 0; m < 4; m++)
#pragma unroll
            for (int n = 0; n < 4; n++)
#pragma unroll
                for (int q = 0; q < 4; q++) {
                    if (tgi[m][q] == tgj[n] && grow[m][q] < gcol[n]) {
                        if (idx < cap) {
                            float sim  = acc[m][n][q];
                            float d2   = mi[m][q] + mj[n] - 2.f * sim;
                            float dist = d2 > 0.f ? sqrtf(d2) : 0.f;
                            uint2 e;
                            e.x = ((unsigned int)grow[m][q] << 16) | (unsigned int)gcol[n];
                            e.y = (unsigned int)__float_as_int(dist);
                            pairs[idx] = e;
                        }
                        idx++;
                    }
                }
    }
}

// row_neg[r] = sum over 32 tile-partials (bf16 -> f32)
__global__ void reduce_kernel(const unsigned short* __restrict__ part,
                              float* __restrict__ row_neg) {
    int r = blockIdx.x * 256 + threadIdx.x;
    float s = 0.f;
#pragma unroll
    for (int k = 0; k < NTILE; k++) s += bf2f(part[(size_t)k * NROWS + r]);
    row_neg[r] = s;
}

__global__ void pair_kernel(const uint2* __restrict__ pairs,
                            const unsigned int* __restrict__ pair_cnt,
                            const float* __restrict__ row_neg,
                            unsigned int cap, double* __restrict__ loss) {
    __shared__ double red[256];
    unsigned int n = *pair_cnt;
    if (n > cap) n = cap;
    double local = 0.0;
    for (unsigned int p = blockIdx.x * blockDim.x + threadIdx.x; p < n;
         p += gridDim.x * blockDim.x) {
        uint2 e = pairs[p];
        int i = (int)(e.x >> 16), j = (int)(e.x & 0xffffu);
        float d = __int_as_float((int)e.y);
        float J = logf(row_neg[i] + row_neg[j]) + d;
        if (J > 0.f) local += (double)J * (double)J;
    }
    red[threadIdx.x] = local;
    __syncthreads();
    for (int s = 128; s; s >>= 1) {
        if (threadIdx.x < (unsigned)s) red[threadIdx.x] += red[threadIdx.x + s];
        __syncthreads();
    }
    if (threadIdx.x == 0) atomicAdd(loss, red[0]);
}

__global__ void fin_kernel(const double* __restrict__ loss,
                           const unsigned int* __restrict__ pair_cnt,
                           float* __restrict__ out) {
    out[0] = (float)(*loss / (2.0 * (double)(*pair_cnt)));
}

extern "C" void kernel_launch(void* const* d_in, const int* in_sizes, int n_in,
                              void* d_out, int out_size, void* d_ws, size_t ws_size,
                              hipStream_t stream) {
    const float* X = (const float*)d_in[0];
    const int* tgt = (const int*)d_in[1];
    float* out = (float*)d_out;

    char* ws = (char*)d_ws;
    float* mag             = (float*)(ws + 0);
    float* row_neg         = (float*)(ws + 16384);
    double* loss           = (double*)(ws + 32768);
    unsigned int* pair_cnt = (unsigned int*)(ws + 32776);
    unsigned short* part   = (unsigned short*)(ws + PART_OFF);
    unsigned short* Xb     = (unsigned short*)(ws + XB_OFF);
    uint2* pairs           = (uint2*)(ws + PAIR_OFF);
    unsigned int cap = 0;
    if (ws_size > PAIR_OFF + 8) cap = (unsigned int)((ws_size - PAIR_OFF) / 8);

    hipMemsetAsync(ws + 32768, 0, 16, stream);  // loss + pair_cnt

    prep_kernel<<<NROWS / 4, 256, 0, stream>>>(X, Xb, mag);

    sim_mfma<<<NBLK, 256, 0, stream>>>(Xb, tgt, mag, part, pair_cnt, pairs, cap);

    reduce_kernel<<<NROWS / 256, 256, 0, stream>>>(part, row_neg);

    pair_kernel<<<256, 256, 0, stream>>>(pairs, pair_cnt, row_neg, cap, loss);

    fin_kernel<<<1, 1, 0, stream>>>(loss, pair_cnt, out);
}

// Round 9
// 70.816 us; speedup vs baseline: 1.2083x; 1.0392x over previous
//
#include <hip/hip_runtime.h>
#include <math.h>

#define NROWS 4096
#define DIM   512
#define BM    128
#define BK    64
#define NKT   (DIM / BK)        // 8
#define NTILE (NROWS / BM)      // 32
#define NBLK  (NTILE * (NTILE + 1) / 2)  // 528 triangular blocks

typedef __attribute__((ext_vector_type(4))) float f32x4;
typedef __attribute__((ext_vector_type(8))) short bf16x8;

// ws layout (bytes):
// [0,      16384)    float mag[4096]
// [16384,  32768)    float row_neg[4096]
// [32768,  32776)    double loss
// [32776,  32780)    unsigned int pair_cnt
// [32780,  32784)    unsigned int done
// [32800,  294944)   ushort part[32][4096]   (bf16 per-tile negsum partials)
// [294944, 4489248)  unsigned short Xb[4096*512]  (bf16 copy of X)
// [4489248, ...)     pairs: uint2 {(i<<16)|j, float_bits(dist)}  8 B each
#define PART_OFF 32800
#define XB_OFF   (PART_OFF + NTILE * NROWS * 2)          // 294944
#define PAIR_OFF (XB_OFF + NROWS * DIM * 2)              // 4489248

__device__ inline unsigned short f2bf(float f) {
    unsigned int u = __float_as_uint(f);
    unsigned int r = (u + 0x7fffu + ((u >> 16) & 1u)) >> 16;   // RTNE
    return (unsigned short)r;
}
__device__ inline float bf2f(unsigned short u) {
    return __uint_as_float((unsigned int)u << 16);
}

// fused: bf16 convert + row sq-norms + zero the control words
__global__ void prep_kernel(const float* __restrict__ X,
                            unsigned short* __restrict__ Xb,
                            float* __restrict__ mag,
                            unsigned int* __restrict__ ctrl) {
    if (blockIdx.x == 0 && threadIdx.x < 4) ctrl[threadIdx.x] = 0u;
    int row  = blockIdx.x * 4 + (threadIdx.x >> 6);
    int lane = threadIdx.x & 63;
    const float4* p = reinterpret_cast<const float4*>(X + (size_t)row * DIM);
    short4* o = reinterpret_cast<short4*>(Xb + (size_t)row * DIM);
    float s = 0.f;
#pragma unroll
    for (int q = lane; q < DIM / 4; q += 64) {
        float4 v = p[q];
        s += v.x * v.x + v.y * v.y + v.z * v.z + v.w * v.w;
        short4 b;
        b.x = (short)f2bf(v.x); b.y = (short)f2bf(v.y);
        b.z = (short)f2bf(v.z); b.w = (short)f2bf(v.w);
        o[q] = b;
    }
#pragma unroll
    for (int off = 32; off; off >>= 1) s += __shfl_down(s, off);
    if (lane == 0) mag[row] = s;
}

__global__ __launch_bounds__(256, 2) void sim_mfma(
        const unsigned short* __restrict__ Xb, const int* __restrict__ tgt,
        const float* __restrict__ mag, unsigned short* __restrict__ part,
        unsigned int* __restrict__ pair_cnt, uint2* __restrict__ pairs,
        unsigned int cap) {
    __shared__ unsigned short As[2][BM * BK];   // 2 x 16 KB
    __shared__ unsigned short Bs[2][BM * BK];   // 2 x 16 KB
    __shared__ float rowbuf[2][BM];
    __shared__ float colbuf[2][BM];
    __shared__ unsigned int scan[8];

    const int tid  = threadIdx.x;
    const int lane = tid & 63;
    const int wid  = tid >> 6;        // 4 waves: 2x2 of 64x64
    const int wr   = wid >> 1, wc = wid & 1;
    const int l15  = lane & 15;
    const int lg   = lane >> 4;       // 0..3

    // triangular block mapping: t -> (bi, bj), bi <= bj (NTILE=32)
    int t = blockIdx.x;
    int bi = (int)((65.0f - sqrtf(4225.0f - 8.0f * (float)t)) * 0.5f);
    if (bi < 0) bi = 0;
    if (bi > NTILE - 1) bi = NTILE - 1;
    while ((65 * (bi + 1) - (bi + 1) * (bi + 1)) / 2 <= t) bi++;
    while ((65 * bi - bi * bi) / 2 > t) bi--;
    int bj = bi + (t - (65 * bi - bi * bi) / 2);
    const int rowBase = bi * BM;
    const int colBase = bj * BM;
    const bool offd = (bi != bj);

    f32x4 acc[4][4];
#pragma unroll
    for (int m = 0; m < 4; m++)
#pragma unroll
        for (int n = 0; n < 4; n++) acc[m][n] = (f32x4){0.f, 0.f, 0.f, 0.f};

    // stage one K-tile (8 global_load_lds per wave); LDS slot (row r, chunk s)
    // holds global chunk s^(r&7) (read-side XOR, linear LDS dest - rule #21)
    auto STAGE = [&](int buf, int kt) {
        const int k0 = kt * BK;
#pragma unroll
        for (int c = 0; c < 4; c++) {
            int chunkBase = (c * 4 + wid) * 64;      // wave-uniform
            int idx = chunkBase + lane;              // 0..1023
            int r   = idx >> 3;
            int ch  = idx & 7;
            int gch = ch ^ (r & 7);
            const unsigned short* ga = Xb + (size_t)(rowBase + r) * DIM + k0 + gch * 8;
            __builtin_amdgcn_global_load_lds(
                (const __attribute__((address_space(1))) void*)ga,
                (__attribute__((address_space(3))) void*)(&As[buf][chunkBase * 8]),
                16, 0, 0);
            const unsigned short* gb = Xb + (size_t)(colBase + r) * DIM + k0 + gch * 8;
            __builtin_amdgcn_global_load_lds(
                (const __attribute__((address_space(1))) void*)gb,
                (__attribute__((address_space(3))) void*)(&Bs[buf][chunkBase * 8]),
                16, 0, 0);
        }
    };

    STAGE(0, 0);   // 8 loads in flight

#pragma unroll
    for (int kt = 0; kt < NKT; kt++) {
        const int cur = kt & 1;
        if (kt + 1 < NKT) {
            STAGE(cur ^ 1, kt + 1);   // +8 -> 16 in flight
            // wait until only the 8 next-tile loads remain (current tile done);
            // NEVER drain to 0 in the loop (T4 counted vmcnt)
            asm volatile("s_waitcnt vmcnt(8)" ::: "memory");
        } else {
            asm volatile("s_waitcnt vmcnt(0)" ::: "memory");   // final peel
        }
        __builtin_amdgcn_s_barrier();
        __builtin_amdgcn_sched_barrier(0);

#pragma unroll
        for (int ksub = 0; ksub < 2; ksub++) {
            bf16x8 af[4], bf[4];
#pragma unroll
            for (int m = 0; m < 4; m++) {
                int ra = wr * 64 + m * 16 + l15;
                int ch = (ksub * 4 + lg) ^ (ra & 7);
                af[m] = *reinterpret_cast<const bf16x8*>(&As[cur][ra * BK + ch * 8]);
            }
#pragma unroll
            for (int n = 0; n < 4; n++) {
                int rb = wc * 64 + n * 16 + l15;
                int ch = (ksub * 4 + lg) ^ (rb & 7);
                bf[n] = *reinterpret_cast<const bf16x8*>(&Bs[cur][rb * BK + ch * 8]);
            }
#pragma unroll
            for (int m = 0; m < 4; m++)
#pragma unroll
                for (int n = 0; n < 4; n++)
                    acc[m][n] = __builtin_amdgcn_mfma_f32_16x16x32_bf16(
                        af[m], bf[n], acc[m][n], 0, 0, 0);
        }
        __builtin_amdgcn_sched_barrier(0);
        __builtin_amdgcn_s_barrier();   // all waves done reading buf[cur]
        __builtin_amdgcn_sched_barrier(0);
    }

    // ---- fused epilogue ----
    // C/D layout: col = lane&15, row = (lane>>4)*4 + reg
    int   gcol[4], tgj[4];
    float mj[4];
#pragma unroll
    for (int n = 0; n < 4; n++) {
        gcol[n] = colBase + wc * 64 + n * 16 + l15;
        tgj[n]  = tgt[gcol[n]];
        mj[n]   = mag[gcol[n]];
    }
    int   grow[4][4], tgi[4][4];
    float mi[4][4];
#pragma unroll
    for (int m = 0; m < 4; m++)
#pragma unroll
        for (int q = 0; q < 4; q++) {
            grow[m][q] = rowBase + wr * 64 + m * 16 + lg * 4 + q;
            tgi[m][q]  = tgt[grow[m][q]];
            mi[m][q]   = mag[grow[m][q]];
        }

    float negrow[4][4];
    float negcol[4] = {0.f, 0.f, 0.f, 0.f};
#pragma unroll
    for (int m = 0; m < 4; m++)
#pragma unroll
        for (int q = 0; q < 4; q++) negrow[m][q] = 0.f;

    int mycnt = 0;
#pragma unroll
    for (int m = 0; m < 4; m++)
#pragma unroll
        for (int n = 0; n < 4; n++)
#pragma unroll
            for (int q = 0; q < 4; q++) {
                float sim  = acc[m][n][q];
                float d2   = mi[m][q] + mj[n] - 2.f * sim;
                float dist = d2 > 0.f ? sqrtf(d2) : 0.f;
                if (tgi[m][q] != tgj[n]) {
                    if (dist != 0.f) {
                        float e = __expf(1.0f - dist);
                        negrow[m][q] += e;
                        if (offd) negcol[n] += e;
                    }
                } else if (grow[m][q] < gcol[n]) {
                    mycnt++;
                }
            }

    __syncthreads();   // LDS (As/Bs) reads done; safe to reuse shared space

    // row-side: reduce across the 16 l15 lanes -> rowbuf[wc][row-local]
#pragma unroll
    for (int m = 0; m < 4; m++)
#pragma unroll
        for (int q = 0; q < 4; q++) {
            float v = negrow[m][q];
            v += __shfl_xor(v, 1); v += __shfl_xor(v, 2);
            v += __shfl_xor(v, 4); v += __shfl_xor(v, 8);
            if (l15 == 0) rowbuf[wc][wr * 64 + m * 16 + lg * 4 + q] = v;
        }
    // col-side: reduce across the 4 lg groups -> colbuf[wr][col-local]
#pragma unroll
    for (int n = 0; n < 4; n++) {
        float v = negcol[n];
        v += __shfl_xor(v, 16); v += __shfl_xor(v, 32);
        if (lg == 0) colbuf[wr][wc * 64 + n * 16 + l15] = v;
    }

    // pair-count scan: wave-level inclusive prefix, then block scan
    unsigned int pc = (unsigned int)mycnt;
    unsigned int incl = pc;
#pragma unroll
    for (int d = 1; d < 64; d <<= 1) {
        unsigned int tshf = __shfl_up(incl, d);
        if (lane >= d) incl += tshf;
    }
    if (lane == 63) scan[wid] = incl;
    __syncthreads();

    // collision-free partial stores: slot part[k][r] written by exactly 1 block
    if (tid < BM) {
        float rv = rowbuf[0][tid] + rowbuf[1][tid];
        part[(size_t)bj * NROWS + rowBase + tid] = f2bf(rv);
        if (offd) {
            float cv = colbuf[0][tid] + colbuf[1][tid];
            part[(size_t)bi * NROWS + colBase + tid] = f2bf(cv);
        }
    }

    unsigned int woff = 0;
#pragma unroll
    for (int w = 0; w < 4; w++)
        if (w < wid) woff += scan[w];
    unsigned int btot = scan[0] + scan[1] + scan[2] + scan[3];
    if (tid == 0) scan[4] = btot ? atomicAdd(pair_cnt, btot) : 0u;
    __syncthreads();
    unsigned int mybase = scan[4] + woff + (incl - pc);

    if (pc) {
        unsigned int idx = mybase;
#pragma unroll
        for (int m = 0; m < 4; m++)
#pragma unroll
            for (int n = 0; n < 4; n++)
#pragma unroll
                for (int q = 0; q < 4; q++) {
                    if (tgi[m][q] == tgj[n] && grow[m][q] < gcol[n]) {
                        if (idx < cap) {
                            float sim  = acc[m][n][q];
                            float d2   = mi[m][q] + mj[n] - 2.f * sim;
                            float dist = d2 > 0.f ? sqrtf(d2) : 0.f;
                            uint2 e;
                            e.x = ((unsigned int)grow[m][q] << 16) | (unsigned int)gcol[n];
                            e.y = (unsigned int)__float_as_int(dist);
                            pairs[idx] = e;
                        }
                        idx++;
                    }
                }
    }
}

// row_neg[r] = sum over 32 tile-partials (bf16 -> f32)
__global__ void reduce_kernel(const unsigned short* __restrict__ part,
                              float* __restrict__ row_neg) {
    int r = blockIdx.x * 256 + threadIdx.x;
    float s = 0.f;
#pragma unroll
    for (int k = 0; k < NTILE; k++) s += bf2f(part[(size_t)k * NROWS + r]);
    row_neg[r] = s;
}

// pair loss sum + last-block finalize (fin fused)
__global__ void pair_kernel(const uint2* __restrict__ pairs,
                            const unsigned int* __restrict__ pair_cnt,
                            const float* __restrict__ row_neg,
                            unsigned int cap, double* __restrict__ loss,
                            unsigned int* __restrict__ done,
                            float* __restrict__ out) {
    __shared__ double red[256];
    unsigned int n = *pair_cnt;
    if (n > cap) n = cap;
    double local = 0.0;
    for (unsigned int p = blockIdx.x * blockDim.x + threadIdx.x; p < n;
         p += gridDim.x * blockDim.x) {
        uint2 e = pairs[p];
        int i = (int)(e.x >> 16), j = (int)(e.x & 0xffffu);
        float d = __int_as_float((int)e.y);
        float J = logf(row_neg[i] + row_neg[j]) + d;
        if (J > 0.f) local += (double)J * (double)J;
    }
    red[threadIdx.x] = local;
    __syncthreads();
    for (int s = 128; s; s >>= 1) {
        if (threadIdx.x < (unsigned)s) red[threadIdx.x] += red[threadIdx.x + s];
        __syncthreads();
    }
    if (threadIdx.x == 0) {
        atomicAdd(loss, red[0]);
        __threadfence();
        unsigned int tk = atomicAdd(done, 1u);
        if (tk == gridDim.x - 1) {
            double l = atomicAdd(loss, 0.0);   // coherent read after all adds
            out[0] = (float)(l / (2.0 * (double)(*pair_cnt)));
        }
    }
}

extern "C" void kernel_launch(void* const* d_in, const int* in_sizes, int n_in,
                              void* d_out, int out_size, void* d_ws, size_t ws_size,
                              hipStream_t stream) {
    const float* X = (const float*)d_in[0];
    const int* tgt = (const int*)d_in[1];
    float* out = (float*)d_out;

    char* ws = (char*)d_ws;
    float* mag             = (float*)(ws + 0);
    float* row_neg         = (float*)(ws + 16384);
    double* loss           = (double*)(ws + 32768);
    unsigned int* pair_cnt = (unsigned int*)(ws + 32776);
    unsigned int* done     = (unsigned int*)(ws + 32780);
    unsigned int* ctrl     = (unsigned int*)(ws + 32768);  // loss+pair_cnt+done
    unsigned short* part   = (unsigned short*)(ws + PART_OFF);
    unsigned short* Xb     = (unsigned short*)(ws + XB_OFF);
    uint2* pairs           = (uint2*)(ws + PAIR_OFF);
    unsigned int cap = 0;
    if (ws_size > PAIR_OFF + 8) cap = (unsigned int)((ws_size - PAIR_OFF) / 8);

    prep_kernel<<<NROWS / 4, 256, 0, stream>>>(X, Xb, mag, ctrl);

    sim_mfma<<<NBLK, 256, 0, stream>>>(Xb, tgt, mag, part, pair_cnt, pairs, cap);

    reduce_kernel<<<NROWS / 256, 256, 0, stream>>>(part, row_neg);

    pair_kernel<<<256, 256, 0, stream>>>(pairs, pair_cnt, row_neg, cap, loss,
                                         done, out);
}

// Round 10
// 54.367 us; speedup vs baseline: 1.5739x; 1.3025x over previous
//
#include <hip/hip_runtime.h>
#include <math.h>

#define NROWS 4096
#define DIM   512
#define BM    128
#define BK    64
#define NKT   (DIM / BK)        // 8
#define NTILE (NROWS / BM)      // 32
#define NBLK  (NTILE * (NTILE + 1) / 2)  // 528 triangular blocks

typedef __attribute__((ext_vector_type(4))) float f32x4;
typedef __attribute__((ext_vector_type(8))) short bf16x8;

// ws layout (bytes):
// [0,      16384)    float mag[4096]
// [32768,  32776)    double loss
// [32776,  32780)    unsigned int pair_cnt
// [32780,  32784)    unsigned int done
// [32800,  294944)   ushort part_t[4096][32]  (bf16 negsum partials, row-major)
// [294944, 4489248)  unsigned short Xb[4096*512]  (bf16 copy of X)
// [4489248, ...)     pairs: uint2 {(i<<16)|j, float_bits(dist)}  8 B each
#define PART_OFF 32800
#define XB_OFF   (PART_OFF + NROWS * NTILE * 2)          // 294944
#define PAIR_OFF (XB_OFF + NROWS * DIM * 2)              // 4489248

__device__ inline unsigned short f2bf(float f) {
    unsigned int u = __float_as_uint(f);
    unsigned int r = (u + 0x7fffu + ((u >> 16) & 1u)) >> 16;   // RTNE
    return (unsigned short)r;
}
__device__ inline float bf2f(unsigned short u) {
    return __uint_as_float((unsigned int)u << 16);
}

// fused: bf16 convert + row sq-norms + zero the control words
__global__ void prep_kernel(const float* __restrict__ X,
                            unsigned short* __restrict__ Xb,
                            float* __restrict__ mag,
                            unsigned int* __restrict__ ctrl) {
    if (blockIdx.x == 0 && threadIdx.x < 4) ctrl[threadIdx.x] = 0u;
    int row  = blockIdx.x * 4 + (threadIdx.x >> 6);
    int lane = threadIdx.x & 63;
    const float4* p = reinterpret_cast<const float4*>(X + (size_t)row * DIM);
    short4* o = reinterpret_cast<short4*>(Xb + (size_t)row * DIM);
    float s = 0.f;
#pragma unroll
    for (int q = lane; q < DIM / 4; q += 64) {
        float4 v = p[q];
        s += v.x * v.x + v.y * v.y + v.z * v.z + v.w * v.w;
        short4 b;
        b.x = (short)f2bf(v.x); b.y = (short)f2bf(v.y);
        b.z = (short)f2bf(v.z); b.w = (short)f2bf(v.w);
        o[q] = b;
    }
#pragma unroll
    for (int off = 32; off; off >>= 1) s += __shfl_down(s, off);
    if (lane == 0) mag[row] = s;
}

__global__ __launch_bounds__(256, 3) void sim_mfma(
        const unsigned short* __restrict__ Xb, const int* __restrict__ tgt,
        const float* __restrict__ mag, unsigned short* __restrict__ part,
        unsigned int* __restrict__ pair_cnt, uint2* __restrict__ pairs,
        unsigned int cap) {
    __shared__ unsigned short As[BM * BK];   // 16 KB
    __shared__ unsigned short Bs[BM * BK];   // 16 KB  (32 KB total)

    const int tid  = threadIdx.x;
    const int lane = tid & 63;
    const int wid  = tid >> 6;        // 4 waves: 2x2 of 64x64
    const int wr   = wid >> 1, wc = wid & 1;
    const int l15  = lane & 15;
    const int lg   = lane >> 4;       // 0..3

    // triangular block mapping: t -> (bi, bj), bi <= bj (NTILE=32)
    int t = blockIdx.x;
    int bi = (int)((65.0f - sqrtf(4225.0f - 8.0f * (float)t)) * 0.5f);
    if (bi < 0) bi = 0;
    if (bi > NTILE - 1) bi = NTILE - 1;
    while ((65 * (bi + 1) - (bi + 1) * (bi + 1)) / 2 <= t) bi++;
    while ((65 * bi - bi * bi) / 2 > t) bi--;
    int bj = bi + (t - (65 * bi - bi * bi) / 2);
    const int rowBase = bi * BM;
    const int colBase = bj * BM;
    const bool offd = (bi != bj);

    f32x4 acc[4][4];
#pragma unroll
    for (int m = 0; m < 4; m++)
#pragma unroll
        for (int n = 0; n < 4; n++) acc[m][n] = (f32x4){0.f, 0.f, 0.f, 0.f};

    // ROLLED K-loop (small I-footprint): sync / stage / sync / compute.
    // LDS slot (row r, chunk s) holds global chunk s^(r&7) (rule #21).
#pragma unroll 1
    for (int kt = 0; kt < NKT; kt++) {
        const int k0 = kt * BK;
        __syncthreads();   // previous iteration's reads done before overwrite
#pragma unroll
        for (int c = 0; c < 4; c++) {
            int chunkBase = (c * 4 + wid) * 64;      // wave-uniform
            int idx = chunkBase + lane;              // 0..1023
            int r   = idx >> 3;
            int ch  = idx & 7;
            int gch = ch ^ (r & 7);
            const unsigned short* ga = Xb + (size_t)(rowBase + r) * DIM + k0 + gch * 8;
            __builtin_amdgcn_global_load_lds(
                (const __attribute__((address_space(1))) void*)ga,
                (__attribute__((address_space(3))) void*)(As + chunkBase * 8),
                16, 0, 0);
            const unsigned short* gb = Xb + (size_t)(colBase + r) * DIM + k0 + gch * 8;
            __builtin_amdgcn_global_load_lds(
                (const __attribute__((address_space(1))) void*)gb,
                (__attribute__((address_space(3))) void*)(Bs + chunkBase * 8),
                16, 0, 0);
        }
        __syncthreads();   // compiler drains vmcnt before barrier

#pragma unroll
        for (int ksub = 0; ksub < 2; ksub++) {
            bf16x8 af[4], bf[4];
#pragma unroll
            for (int m = 0; m < 4; m++) {
                int ra = wr * 64 + m * 16 + l15;
                int ch = (ksub * 4 + lg) ^ (ra & 7);
                af[m] = *reinterpret_cast<const bf16x8*>(&As[ra * BK + ch * 8]);
            }
#pragma unroll
            for (int n = 0; n < 4; n++) {
                int rb = wc * 64 + n * 16 + l15;
                int ch = (ksub * 4 + lg) ^ (rb & 7);
                bf[n] = *reinterpret_cast<const bf16x8*>(&Bs[rb * BK + ch * 8]);
            }
#pragma unroll
            for (int m = 0; m < 4; m++)
#pragma unroll
                for (int n = 0; n < 4; n++)
                    acc[m][n] = __builtin_amdgcn_mfma_f32_16x16x32_bf16(
                        af[m], bf[n], acc[m][n], 0, 0, 0);
        }
    }

    // ---- fused epilogue ----
    // C/D layout: col = lane&15, row = (lane>>4)*4 + reg
    int   gcol[4], tgj[4];
    float mj[4];
#pragma unroll
    for (int n = 0; n < 4; n++) {
        gcol[n] = colBase + wc * 64 + n * 16 + l15;
        tgj[n]  = tgt[gcol[n]];
        mj[n]   = mag[gcol[n]];
    }
    int   grow[4][4], tgi[4][4];
    float mi[4][4];
#pragma unroll
    for (int m = 0; m < 4; m++)
#pragma unroll
        for (int q = 0; q < 4; q++) {
            grow[m][q] = rowBase + wr * 64 + m * 16 + lg * 4 + q;
            tgi[m][q]  = tgt[grow[m][q]];
            mi[m][q]   = mag[grow[m][q]];
        }

    float negrow[4][4];
    float negcol[4] = {0.f, 0.f, 0.f, 0.f};
#pragma unroll
    for (int m = 0; m < 4; m++)
#pragma unroll
        for (int q = 0; q < 4; q++) negrow[m][q] = 0.f;

    // pass A: dist (overwrites acc), negsum accumulation, positive count
    int mycnt = 0;
#pragma unroll
    for (int m = 0; m < 4; m++)
#pragma unroll
        for (int n = 0; n < 4; n++)
#pragma unroll
            for (int q = 0; q < 4; q++) {
                float d2   = mi[m][q] + mj[n] - 2.f * acc[m][n][q];
                float dist = d2 > 0.f ? sqrtf(d2) : 0.f;
                acc[m][n][q] = dist;
                bool same = (tgi[m][q] == tgj[n]);
                if (!same) {
                    if (dist != 0.f) {
                        float e = __expf(1.0f - dist);
                        negrow[m][q] += e;
                        if (offd) negcol[n] += e;
                    }
                } else if (grow[m][q] < gcol[n]) {
                    mycnt++;
                }
            }

    __syncthreads();   // K-loop LDS reads done; overlay epilogue buffers
    float* rowbuf = (float*)&As[0];            // [2][128] floats, 1 KB
    float* colbuf = (float*)&As[1024];         // [2][128] floats, 1 KB
    unsigned int* scan = (unsigned int*)&Bs[0];

    // row-side: reduce across the 16 l15 lanes -> rowbuf[wc*128 + rowLocal]
#pragma unroll
    for (int m = 0; m < 4; m++)
#pragma unroll
        for (int q = 0; q < 4; q++) {
            float v = negrow[m][q];
            v += __shfl_xor(v, 1); v += __shfl_xor(v, 2);
            v += __shfl_xor(v, 4); v += __shfl_xor(v, 8);
            if (l15 == 0) rowbuf[wc * 128 + wr * 64 + m * 16 + lg * 4 + q] = v;
        }
    // col-side: reduce across the 4 lg groups -> colbuf[wr*128 + colLocal]
#pragma unroll
    for (int n = 0; n < 4; n++) {
        float v = negcol[n];
        v += __shfl_xor(v, 16); v += __shfl_xor(v, 32);
        if (lg == 0) colbuf[wr * 128 + wc * 64 + n * 16 + l15] = v;
    }

    // pair-count scan: wave-level inclusive prefix, then block scan
    unsigned int pc = (unsigned int)mycnt;
    unsigned int incl = pc;
#pragma unroll
    for (int d = 1; d < 64; d <<= 1) {
        unsigned int tshf = __shfl_up(incl, d);
        if (lane >= d) incl += tshf;
    }
    if (lane == 63) scan[wid] = incl;
    __syncthreads();

    // collision-free transposed partial stores: part_t[row][tile]
    if (tid < BM) {
        float rv = rowbuf[tid] + rowbuf[128 + tid];
        part[(size_t)(rowBase + tid) * NTILE + bj] = f2bf(rv);
        if (offd) {
            float cv = colbuf[tid] + colbuf[128 + tid];
            part[(size_t)(colBase + tid) * NTILE + bi] = f2bf(cv);
        }
    }

    unsigned int woff = 0;
#pragma unroll
    for (int w = 0; w < 4; w++)
        if (w < wid) woff += scan[w];
    unsigned int btot = scan[0] + scan[1] + scan[2] + scan[3];
    if (tid == 0) scan[4] = btot ? atomicAdd(pair_cnt, btot) : 0u;
    __syncthreads();
    unsigned int mybase = scan[4] + woff + (incl - pc);

    // pass B: write pairs (dist already in acc)
    if (pc) {
        unsigned int idx = mybase;
#pragma unroll
        for (int m = 0; m < 4; m++)
#pragma unroll
            for (int n = 0; n < 4; n++)
#pragma unroll
                for (int q = 0; q < 4; q++) {
                    if (tgi[m][q] == tgj[n] && grow[m][q] < gcol[n]) {
                        if (idx < cap) {
                            uint2 e;
                            e.x = ((unsigned int)grow[m][q] << 16) | (unsigned int)gcol[n];
                            e.y = (unsigned int)__float_as_int(acc[m][n][q]);
                            pairs[idx] = e;
                        }
                        idx++;
                    }
                }
    }
}

// pair loss sum with inline row_neg gather (64B/row, L2-hot) + fused finalize
__global__ void pair_kernel(const uint2* __restrict__ pairs,
                            const unsigned int* __restrict__ pair_cnt,
                            const unsigned short* __restrict__ part,
                            unsigned int cap, double* __restrict__ loss,
                            unsigned int* __restrict__ done,
                            float* __restrict__ out) {
    __shared__ double red[256];
    unsigned int n = *pair_cnt;
    if (n > cap) n = cap;
    double local = 0.0;
    for (unsigned int p = blockIdx.x * blockDim.x + threadIdx.x; p < n;
         p += gridDim.x * blockDim.x) {
        uint2 e = pairs[p];
        int i = (int)(e.x >> 16), j = (int)(e.x & 0xffffu);
        float d = __int_as_float((int)e.y);
        const bf16x8* pi = reinterpret_cast<const bf16x8*>(part + (size_t)i * NTILE);
        const bf16x8* pj = reinterpret_cast<const bf16x8*>(part + (size_t)j * NTILE);
        float ni = 0.f, nj = 0.f;
#pragma unroll
        for (int k = 0; k < 4; k++) {
            bf16x8 a = pi[k], b = pj[k];
#pragma unroll
            for (int u = 0; u < 8; u++) {
                ni += bf2f((unsigned short)a[u]);
                nj += bf2f((unsigned short)b[u]);
            }
        }
        float J = logf(ni + nj) + d;
        if (J > 0.f) local += (double)J * (double)J;
    }
    red[threadIdx.x] = local;
    __syncthreads();
    for (int s = 128; s; s >>= 1) {
        if (threadIdx.x < (unsigned)s) red[threadIdx.x] += red[threadIdx.x + s];
        __syncthreads();
    }
    if (threadIdx.x == 0) {
        atomicAdd(loss, red[0]);
        __threadfence();
        unsigned int tk = atomicAdd(done, 1u);
        if (tk == gridDim.x - 1) {
            double l = atomicAdd(loss, 0.0);   // coherent read after all adds
            out[0] = (float)(l / (2.0 * (double)(*pair_cnt)));
        }
    }
}

extern "C" void kernel_launch(void* const* d_in, const int* in_sizes, int n_in,
                              void* d_out, int out_size, void* d_ws, size_t ws_size,
                              hipStream_t stream) {
    const float* X = (const float*)d_in[0];
    const int* tgt = (const int*)d_in[1];
    float* out = (float*)d_out;

    char* ws = (char*)d_ws;
    float* mag             = (float*)(ws + 0);
    double* loss           = (double*)(ws + 32768);
    unsigned int* pair_cnt = (unsigned int*)(ws + 32776);
    unsigned int* done     = (unsigned int*)(ws + 32780);
    unsigned int* ctrl     = (unsigned int*)(ws + 32768);  // loss+pair_cnt+done
    unsigned short* part   = (unsigned short*)(ws + PART_OFF);
    unsigned short* Xb     = (unsigned short*)(ws + XB_OFF);
    uint2* pairs           = (uint2*)(ws + PAIR_OFF);
    unsigned int cap = 0;
    if (ws_size > PAIR_OFF + 8) cap = (unsigned int)((ws_size - PAIR_OFF) / 8);

    prep_kernel<<<NROWS / 4, 256, 0, stream>>>(X, Xb, mag, ctrl);

    sim_mfma<<<NBLK, 256, 0, stream>>>(Xb, tgt, mag, part, pair_cnt, pairs, cap);

    pair_kernel<<<256, 256, 0, stream>>>(pairs, pair_cnt, part, cap, loss,
                                         done, out);
}

// Round 11
// 53.735 us; speedup vs baseline: 1.5924x; 1.0118x over previous
//
#include <hip/hip_runtime.h>
#include <math.h>

#define NROWS 4096
#define DIM   512
#define BM    128
#define BK    64
#define NKT   (DIM / BK)        // 8
#define NTILE (NROWS / BM)      // 32
#define NBLK  (NTILE * (NTILE + 1) / 2)  // 528 triangular blocks (= 8 x 66)

typedef __attribute__((ext_vector_type(4))) float f32x4;
typedef __attribute__((ext_vector_type(8))) short bf16x8;

// ws layout (bytes):
// [0,      16384)    float mag[4096]
// [16384,  32768)    float row_neg[4096]
// [32768,  32776)    double loss
// [32776,  32780)    unsigned int pair_cnt
// [32780,  32784)    unsigned int done
// [32800,  294944)   ushort part_t[4096][32]  (bf16 negsum partials, row-major)
// [294944, 4489248)  unsigned short Xb[4096*512]  (bf16 copy of X)
// [4489248, ...)     pairs: uint2 {(i<<16)|j, float_bits(dist)}  8 B each
#define PART_OFF 32800
#define XB_OFF   (PART_OFF + NROWS * NTILE * 2)          // 294944
#define PAIR_OFF (XB_OFF + NROWS * DIM * 2)              // 4489248

__device__ inline unsigned short f2bf(float f) {
    unsigned int u = __float_as_uint(f);
    unsigned int r = (u + 0x7fffu + ((u >> 16) & 1u)) >> 16;   // RTNE
    return (unsigned short)r;
}
__device__ inline float bf2f(unsigned short u) {
    return __uint_as_float((unsigned int)u << 16);
}

// fused: bf16 convert + row sq-norms + zero the control words
__global__ void prep_kernel(const float* __restrict__ X,
                            unsigned short* __restrict__ Xb,
                            float* __restrict__ mag,
                            unsigned int* __restrict__ ctrl) {
    if (blockIdx.x == 0 && threadIdx.x < 4) ctrl[threadIdx.x] = 0u;
    int row  = blockIdx.x * 4 + (threadIdx.x >> 6);
    int lane = threadIdx.x & 63;
    const float4* p = reinterpret_cast<const float4*>(X + (size_t)row * DIM);
    short4* o = reinterpret_cast<short4*>(Xb + (size_t)row * DIM);
    float s = 0.f;
#pragma unroll
    for (int q = lane; q < DIM / 4; q += 64) {
        float4 v = p[q];
        s += v.x * v.x + v.y * v.y + v.z * v.z + v.w * v.w;
        short4 b;
        b.x = (short)f2bf(v.x); b.y = (short)f2bf(v.y);
        b.z = (short)f2bf(v.z); b.w = (short)f2bf(v.w);
        o[q] = b;
    }
#pragma unroll
    for (int off = 32; off; off >>= 1) s += __shfl_down(s, off);
    if (lane == 0) mag[row] = s;
}

__global__ __launch_bounds__(256, 3) void sim_mfma(
        const unsigned short* __restrict__ Xb, const int* __restrict__ tgt,
        const float* __restrict__ mag, unsigned short* __restrict__ part,
        unsigned int* __restrict__ pair_cnt, uint2* __restrict__ pairs,
        unsigned int cap) {
    __shared__ unsigned short As[BM * BK];   // 16 KB
    __shared__ unsigned short Bs[BM * BK];   // 16 KB  (32 KB total)

    const int tid  = threadIdx.x;
    const int lane = tid & 63;
    const int wid  = tid >> 6;        // 4 waves: 2x2 of 64x64
    const int wr   = wid >> 1, wc = wid & 1;
    const int l15  = lane & 15;
    const int lg   = lane >> 4;       // 0..3

    // XCD-aware bijective swizzle: 528 = 8 x 66, each XCD gets 66 consecutive
    // triangular tiles (shared A-panels stay in that XCD's L2)
    int b = blockIdx.x;
    int t = (b & 7) * 66 + (b >> 3);

    // triangular block mapping: t -> (bi, bj), bi <= bj (NTILE=32)
    int bi = (int)((65.0f - sqrtf(4225.0f - 8.0f * (float)t)) * 0.5f);
    if (bi < 0) bi = 0;
    if (bi > NTILE - 1) bi = NTILE - 1;
    while ((65 * (bi + 1) - (bi + 1) * (bi + 1)) / 2 <= t) bi++;
    while ((65 * bi - bi * bi) / 2 > t) bi--;
    int bj = bi + (t - (65 * bi - bi * bi) / 2);
    const int rowBase = bi * BM;
    const int colBase = bj * BM;
    const bool offd = (bi != bj);

    f32x4 acc[4][4];
#pragma unroll
    for (int m = 0; m < 4; m++)
#pragma unroll
        for (int n = 0; n < 4; n++) acc[m][n] = (f32x4){0.f, 0.f, 0.f, 0.f};

    // ROLLED K-loop (small I-footprint): sync / stage / sync / compute.
    // LDS slot (row r, chunk s) holds global chunk s^(r&7) (rule #21).
#pragma unroll 1
    for (int kt = 0; kt < NKT; kt++) {
        const int k0 = kt * BK;
        __syncthreads();   // previous iteration's reads done before overwrite
#pragma unroll
        for (int c = 0; c < 4; c++) {
            int chunkBase = (c * 4 + wid) * 64;      // wave-uniform
            int idx = chunkBase + lane;              // 0..1023
            int r   = idx >> 3;
            int ch  = idx & 7;
            int gch = ch ^ (r & 7);
            const unsigned short* ga = Xb + (size_t)(rowBase + r) * DIM + k0 + gch * 8;
            __builtin_amdgcn_global_load_lds(
                (const __attribute__((address_space(1))) void*)ga,
                (__attribute__((address_space(3))) void*)(As + chunkBase * 8),
                16, 0, 0);
            const unsigned short* gb = Xb + (size_t)(colBase + r) * DIM + k0 + gch * 8;
            __builtin_amdgcn_global_load_lds(
                (const __attribute__((address_space(1))) void*)gb,
                (__attribute__((address_space(3))) void*)(Bs + chunkBase * 8),
                16, 0, 0);
        }
        __syncthreads();   // compiler drains vmcnt before barrier

#pragma unroll
        for (int ksub = 0; ksub < 2; ksub++) {
            bf16x8 af[4], bf[4];
#pragma unroll
            for (int m = 0; m < 4; m++) {
                int ra = wr * 64 + m * 16 + l15;
                int ch = (ksub * 4 + lg) ^ (ra & 7);
                af[m] = *reinterpret_cast<const bf16x8*>(&As[ra * BK + ch * 8]);
            }
#pragma unroll
            for (int n = 0; n < 4; n++) {
                int rb = wc * 64 + n * 16 + l15;
                int ch = (ksub * 4 + lg) ^ (rb & 7);
                bf[n] = *reinterpret_cast<const bf16x8*>(&Bs[rb * BK + ch * 8]);
            }
#pragma unroll
            for (int m = 0; m < 4; m++)
#pragma unroll
                for (int n = 0; n < 4; n++)
                    acc[m][n] = __builtin_amdgcn_mfma_f32_16x16x32_bf16(
                        af[m], bf[n], acc[m][n], 0, 0, 0);
        }
    }

    // ---- fused epilogue ----
    // C/D layout: col = lane&15, row = (lane>>4)*4 + reg
    int   gcol[4], tgj[4];
    float mj[4];
#pragma unroll
    for (int n = 0; n < 4; n++) {
        gcol[n] = colBase + wc * 64 + n * 16 + l15;
        tgj[n]  = tgt[gcol[n]];
        mj[n]   = mag[gcol[n]];
    }
    int   grow[4][4], tgi[4][4];
    float mi[4][4];
#pragma unroll
    for (int m = 0; m < 4; m++)
#pragma unroll
        for (int q = 0; q < 4; q++) {
            grow[m][q] = rowBase + wr * 64 + m * 16 + lg * 4 + q;
            tgi[m][q]  = tgt[grow[m][q]];
            mi[m][q]   = mag[grow[m][q]];
        }

    float negrow[4][4];
    float negcol[4] = {0.f, 0.f, 0.f, 0.f};
#pragma unroll
    for (int m = 0; m < 4; m++)
#pragma unroll
        for (int q = 0; q < 4; q++) negrow[m][q] = 0.f;

    // pass A: dist (overwrites acc), negsum accumulation, positive count
    int mycnt = 0;
#pragma unroll
    for (int m = 0; m < 4; m++)
#pragma unroll
        for (int n = 0; n < 4; n++)
#pragma unroll
            for (int q = 0; q < 4; q++) {
                float d2   = mi[m][q] + mj[n] - 2.f * acc[m][n][q];
                float dist = d2 > 0.f ? sqrtf(d2) : 0.f;
                acc[m][n][q] = dist;
                bool same = (tgi[m][q] == tgj[n]);
                if (!same) {
                    if (dist != 0.f) {
                        float e = __expf(1.0f - dist);
                        negrow[m][q] += e;
                        if (offd) negcol[n] += e;
                    }
                } else if (grow[m][q] < gcol[n]) {
                    mycnt++;
                }
            }

    __syncthreads();   // K-loop LDS reads done; overlay epilogue buffers
    float* rowbuf = (float*)&As[0];            // [2][128] floats, 1 KB
    float* colbuf = (float*)&As[1024];         // [2][128] floats, 1 KB
    unsigned int* scan = (unsigned int*)&Bs[0];

    // row-side: reduce across the 16 l15 lanes -> rowbuf[wc*128 + rowLocal]
#pragma unroll
    for (int m = 0; m < 4; m++)
#pragma unroll
        for (int q = 0; q < 4; q++) {
            float v = negrow[m][q];
            v += __shfl_xor(v, 1); v += __shfl_xor(v, 2);
            v += __shfl_xor(v, 4); v += __shfl_xor(v, 8);
            if (l15 == 0) rowbuf[wc * 128 + wr * 64 + m * 16 + lg * 4 + q] = v;
        }
    // col-side: reduce across the 4 lg groups -> colbuf[wr*128 + colLocal]
#pragma unroll
    for (int n = 0; n < 4; n++) {
        float v = negcol[n];
        v += __shfl_xor(v, 16); v += __shfl_xor(v, 32);
        if (lg == 0) colbuf[wr * 128 + wc * 64 + n * 16 + l15] = v;
    }

    // pair-count scan: wave-level inclusive prefix, then block scan
    unsigned int pc = (unsigned int)mycnt;
    unsigned int incl = pc;
#pragma unroll
    for (int d = 1; d < 64; d <<= 1) {
        unsigned int tshf = __shfl_up(incl, d);
        if (lane >= d) incl += tshf;
    }
    if (lane == 63) scan[wid] = incl;
    __syncthreads();

    // collision-free transposed partial stores: part_t[row][tile]
    if (tid < BM) {
        float rv = rowbuf[tid] + rowbuf[128 + tid];
        part[(size_t)(rowBase + tid) * NTILE + bj] = f2bf(rv);
        if (offd) {
            float cv = colbuf[tid] + colbuf[128 + tid];
            part[(size_t)(colBase + tid) * NTILE + bi] = f2bf(cv);
        }
    }

    unsigned int woff = 0;
#pragma unroll
    for (int w = 0; w < 4; w++)
        if (w < wid) woff += scan[w];
    unsigned int btot = scan[0] + scan[1] + scan[2] + scan[3];
    if (tid == 0) scan[4] = btot ? atomicAdd(pair_cnt, btot) : 0u;
    __syncthreads();
    unsigned int mybase = scan[4] + woff + (incl - pc);

    // pass B: write pairs (dist already in acc)
    if (pc) {
        unsigned int idx = mybase;
#pragma unroll
        for (int m = 0; m < 4; m++)
#pragma unroll
            for (int n = 0; n < 4; n++)
#pragma unroll
                for (int q = 0; q < 4; q++) {
                    if (tgi[m][q] == tgj[n] && grow[m][q] < gcol[n]) {
                        if (idx < cap) {
                            uint2 e;
                            e.x = ((unsigned int)grow[m][q] << 16) | (unsigned int)gcol[n];
                            e.y = (unsigned int)__float_as_int(acc[m][n][q]);
                            pairs[idx] = e;
                        }
                        idx++;
                    }
                }
    }
}

// row_neg[r] = sum of 32 bf16 partials (contiguous 64B stripe per row)
__global__ void reduce_kernel(const unsigned short* __restrict__ part,
                              float* __restrict__ row_neg) {
    int r = blockIdx.x * 256 + threadIdx.x;
    const bf16x8* p = reinterpret_cast<const bf16x8*>(part + (size_t)r * NTILE);
    float s = 0.f;
#pragma unroll
    for (int k = 0; k < 4; k++) {
        bf16x8 a = p[k];
#pragma unroll
        for (int u = 0; u < 8; u++) s += bf2f((unsigned short)a[u]);
    }
    row_neg[r] = s;
}

// pair loss sum + fused finalize
__global__ void pair_kernel(const uint2* __restrict__ pairs,
                            const unsigned int* __restrict__ pair_cnt,
                            const float* __restrict__ row_neg,
                            unsigned int cap, double* __restrict__ loss,
                            unsigned int* __restrict__ done,
                            float* __restrict__ out) {
    __shared__ double red[256];
    unsigned int n = *pair_cnt;
    if (n > cap) n = cap;
    double local = 0.0;
    for (unsigned int p = blockIdx.x * blockDim.x + threadIdx.x; p < n;
         p += gridDim.x * blockDim.x) {
        uint2 e = pairs[p];
        int i = (int)(e.x >> 16), j = (int)(e.x & 0xffffu);
        float d = __int_as_float((int)e.y);
        float J = logf(row_neg[i] + row_neg[j]) + d;
        if (J > 0.f) local += (double)J * (double)J;
    }
    red[threadIdx.x] = local;
    __syncthreads();
    for (int s = 128; s; s >>= 1) {
        if (threadIdx.x < (unsigned)s) red[threadIdx.x] += red[threadIdx.x + s];
        __syncthreads();
    }
    if (threadIdx.x == 0) {
        atomicAdd(loss, red[0]);
        __threadfence();
        unsigned int tk = atomicAdd(done, 1u);
        if (tk == gridDim.x - 1) {
            double l = atomicAdd(loss, 0.0);   // coherent read after all adds
            out[0] = (float)(l / (2.0 * (double)(*pair_cnt)));
        }
    }
}

extern "C" void kernel_launch(void* const* d_in, const int* in_sizes, int n_in,
                              void* d_out, int out_size, void* d_ws, size_t ws_size,
                              hipStream_t stream) {
    const float* X = (const float*)d_in[0];
    const int* tgt = (const int*)d_in[1];
    float* out = (float*)d_out;

    char* ws = (char*)d_ws;
    float* mag             = (float*)(ws + 0);
    float* row_neg         = (float*)(ws + 16384);
    double* loss           = (double*)(ws + 32768);
    unsigned int* pair_cnt = (unsigned int*)(ws + 32776);
    unsigned int* done     = (unsigned int*)(ws + 32780);
    unsigned int* ctrl     = (unsigned int*)(ws + 32768);  // loss+pair_cnt+done
    unsigned short* part   = (unsigned short*)(ws + PART_OFF);
    unsigned short* Xb     = (unsigned short*)(ws + XB_OFF);
    uint2* pairs           = (uint2*)(ws + PAIR_OFF);
    unsigned int cap = 0;
    if (ws_size > PAIR_OFF + 8) cap = (unsigned int)((ws_size - PAIR_OFF) / 8);

    prep_kernel<<<NROWS / 4, 256, 0, stream>>>(X, Xb, mag, ctrl);

    sim_mfma<<<NBLK, 256, 0, stream>>>(Xb, tgt, mag, part, pair_cnt, pairs, cap);

    reduce_kernel<<<NROWS / 256, 256, 0, stream>>>(part, row_neg);

    pair_kernel<<<256, 256, 0, stream>>>(pairs, pair_cnt, row_neg, cap, loss,
                                         done, out);
}